// Round 14
// baseline (75.467 us; speedup 1.0000x reference)
//
#include <hip/hip_runtime.h>

#define Hn 768
#define Bn 16
#define Sn 512
#define En 32
#define Vn 50265

#define KC   4            // k-chunks (split-K across blocks)
#define KPB  (Hn / KC)    // 192 k per block
#define VT   1024         // v per block (256 threads x 4 v float4)
#define NVT  50           // v tiles (50 * 1024 = 51200 >= Vn)
#define VNP  (NVT * VT)   // padded V for partials

// ---------------- Layer 1: o1 = g1*inst + (1-g1)*sent, g1 = sigmoid(inst@W1_1 + sent@W1_2)
__global__ __launch_bounds__(256) void gate_layer1(
    const int* __restrict__ batch_arg, const int* __restrict__ event_pos,
    const int* __restrict__ mask_indices, const float* __restrict__ sent_emb,
    const float* __restrict__ emb_table, const float* __restrict__ W1_1,
    const float* __restrict__ W1_2, float* __restrict__ o1_out)
{
    const int b  = blockIdx.x;
    const int j0 = threadIdx.x & 63;
    const int ks = threadIdx.x >> 6;           // wave-uniform
    const int j  = blockIdx.y * 64 + j0;

    const int mask = mask_indices[b];
    int estar = -1;
    #pragma unroll
    for (int e = 0; e < En; ++e)
        if (event_pos[b * En + e] == mask && estar < 0) estar = e;
    const int tok = batch_arg[b * Sn + mask];

    __shared__ __align__(16) float s_inst[Hn];
    __shared__ __align__(16) float s_sent[Hn];
    for (int t = threadIdx.x; t < Hn; t += 256) {
        s_inst[t] = emb_table[(size_t)tok * Hn + t];
        s_sent[t] = (estar >= 0) ? sent_emb[((size_t)b * En + estar) * Hn + t] : 0.f;
    }
    __syncthreads();

    float a0 = 0.f, a1 = 0.f, c0 = 0.f, c1 = 0.f;
    const float* __restrict__ w1 = W1_1 + (size_t)ks * 192 * Hn + j;
    const float* __restrict__ w2 = W1_2 + (size_t)ks * 192 * Hn + j;
    const float4* __restrict__ si = (const float4*)(s_inst + ks * 192);
    const float4* __restrict__ ss = (const float4*)(s_sent + ks * 192);
    #pragma unroll 4
    for (int k4 = 0; k4 < 48; ++k4) {
        const float4 iv = si[k4];
        const float4 sv = ss[k4];
        const float* __restrict__ wa = w1 + (size_t)k4 * 4 * Hn;
        const float* __restrict__ wb = w2 + (size_t)k4 * 4 * Hn;
        a0 = fmaf(iv.x, wa[0],      a0);
        a1 = fmaf(iv.y, wa[Hn],     a1);
        a0 = fmaf(iv.z, wa[2 * Hn], a0);
        a1 = fmaf(iv.w, wa[3 * Hn], a1);
        c0 = fmaf(sv.x, wb[0],      c0);
        c1 = fmaf(sv.y, wb[Hn],     c1);
        c0 = fmaf(sv.z, wb[2 * Hn], c0);
        c1 = fmaf(sv.w, wb[3 * Hn], c1);
    }

    __shared__ float r_a[4][64];
    __shared__ float r_c[4][64];
    r_a[ks][j0] = a0 + a1; r_c[ks][j0] = c0 + c1;
    __syncthreads();
    if (ks == 0) {
        const float A = r_a[0][j0] + r_a[1][j0] + r_a[2][j0] + r_a[3][j0];
        const float C = r_c[0][j0] + r_c[1][j0] + r_c[2][j0] + r_c[3][j0];
        const float g = 1.f / (1.f + expf(-(A + C)));
        o1_out[b * Hn + j] = g * s_inst[j] + (1.f - g) * s_sent[j];
    }
}

// ---------------- Layer 2: o2 = g2*o1 + (1-g2)*typ, written TRANSPOSED as me_t[k][b]
__global__ __launch_bounds__(256) void gate_layer2(
    const int* __restrict__ batch_arg, const int* __restrict__ event_pos,
    const int* __restrict__ mask_indices, const float* __restrict__ type_emb,
    const float* __restrict__ emb_table, const float* __restrict__ W2_1,
    const float* __restrict__ W2_2, const float* __restrict__ o1_in,
    float* __restrict__ me_t)
{
    const int b  = blockIdx.x;
    const int j0 = threadIdx.x & 63;
    const int ks = threadIdx.x >> 6;
    const int j  = blockIdx.y * 64 + j0;

    const int mask = mask_indices[b];
    int estar = -1;
    #pragma unroll
    for (int e = 0; e < En; ++e)
        if (event_pos[b * En + e] == mask && estar < 0) estar = e;
    const int tok = batch_arg[b * Sn + mask];

    __shared__ __align__(16) float s_o1[Hn];
    __shared__ __align__(16) float s_typ[Hn];
    for (int t = threadIdx.x; t < Hn; t += 256) {
        s_o1[t]  = o1_in[b * Hn + t];
        s_typ[t] = type_emb[((size_t)b * Sn + mask) * Hn + t];
    }
    __syncthreads();

    float a0 = 0.f, a1 = 0.f, c0 = 0.f, c1 = 0.f;
    const float* __restrict__ w1 = W2_1 + (size_t)ks * 192 * Hn + j;
    const float* __restrict__ w2 = W2_2 + (size_t)ks * 192 * Hn + j;
    const float4* __restrict__ so = (const float4*)(s_o1  + ks * 192);
    const float4* __restrict__ st = (const float4*)(s_typ + ks * 192);
    #pragma unroll 4
    for (int k4 = 0; k4 < 48; ++k4) {
        const float4 ov = so[k4];
        const float4 tv = st[k4];
        const float* __restrict__ wa = w1 + (size_t)k4 * 4 * Hn;
        const float* __restrict__ wb = w2 + (size_t)k4 * 4 * Hn;
        a0 = fmaf(ov.x, wa[0],      a0);
        a1 = fmaf(ov.y, wa[Hn],     a1);
        a0 = fmaf(ov.z, wa[2 * Hn], a0);
        a1 = fmaf(ov.w, wa[3 * Hn], a1);
        c0 = fmaf(tv.x, wb[0],      c0);
        c1 = fmaf(tv.y, wb[Hn],     c1);
        c0 = fmaf(tv.z, wb[2 * Hn], c0);
        c1 = fmaf(tv.w, wb[3 * Hn], c1);
    }

    __shared__ float r_a[4][64];
    __shared__ float r_c[4][64];
    r_a[ks][j0] = a0 + a1; r_c[ks][j0] = c0 + c1;
    __syncthreads();
    if (ks == 0) {
        const float A = r_a[0][j0] + r_a[1][j0] + r_a[2][j0] + r_a[3][j0];
        const float C = r_c[0][j0] + r_c[1][j0] + r_c[2][j0] + r_c[3][j0];
        const float g = 1.f / (1.f + expf(-(A + C)));
        float o2 = g * s_o1[j] + (1.f - g) * s_typ[j];
        if (estar < 0) o2 = emb_table[(size_t)tok * Hn + j];  // mask row never updated
        me_t[j * Bn + b] = o2;
    }
}

// ---------------- LM head partials: partial[kc][b][v] = sum_{k in chunk} me[k][b]*lm_W[k][v]
// Grid (50, 4) = 200 blocks x 256 threads: <=1 block/CU (no makespan tail), all
// co-resident. Thread = 4 v (float4) x 16 b, 64-VGPR acc, no cross-wave reduce.
// Ring-6 named prefetch: slot s reloaded right after its FMAs -> counted vmcnt
// waits (never drains); 51.2k threads x 96 B ~ 4.9 MB in flight chip-wide.
// Block reads 4 KB contiguous per k-row (DRAM-burst friendly).
__global__ __launch_bounds__(256, 2) void lm_head_stream(
    const float* __restrict__ me_t, const float* __restrict__ lm_W,
    float* __restrict__ partial)
{
    __shared__ __align__(16) float s_me[KPB * Bn];   // 12 KB me slice for this chunk

    const int tid = threadIdx.x;
    const int kc  = blockIdx.y;
    const int kb  = kc * KPB;
    const int v0  = blockIdx.x * VT + tid * 4;

    for (int i = tid; i < KPB * Bn / 4; i += 256)    // 768 float4, coalesced
        ((float4*)s_me)[i] = ((const float4*)(me_t + kb * Bn))[i];
    __syncthreads();

    float4 acc[Bn];
    #pragma unroll
    for (int i = 0; i < Bn; ++i) acc[i] = make_float4(0.f, 0.f, 0.f, 0.f);

#define FMA4(i, s)                                                            \
    acc[i].x = fmaf(s, wv.x, acc[i].x); acc[i].y = fmaf(s, wv.y, acc[i].y);   \
    acc[i].z = fmaf(s, wv.z, acc[i].z); acc[i].w = fmaf(s, wv.w, acc[i].w);

#define FMAROW(kk, wreg)                                                      \
    {                                                                         \
        const float4 wv = wreg;                                               \
        const float4* __restrict__ m = (const float4*)(s_me + (kk) * Bn);     \
        const float4 m0 = m[0], m1 = m[1], m2 = m[2], m3 = m[3];              \
        FMA4(0,  m0.x) FMA4(1,  m0.y) FMA4(2,  m0.z) FMA4(3,  m0.w)          \
        FMA4(4,  m1.x) FMA4(5,  m1.y) FMA4(6,  m1.z) FMA4(7,  m1.w)          \
        FMA4(8,  m2.x) FMA4(9,  m2.y) FMA4(10, m2.z) FMA4(11, m2.w)          \
        FMA4(12, m3.x) FMA4(13, m3.y) FMA4(14, m3.z) FMA4(15, m3.w)          \
    }

    if (v0 + 3 < Vn) {
        const float* __restrict__ wp = lm_W + (size_t)kb * Vn + v0;
#define LROW(kk) (*(const float4*)(wp + (size_t)(kk) * Vn))
#define LCL(kk)  LROW((kk) < KPB ? (kk) : (KPB - 1))   // clamped (redundant at tail)
        float4 w0 = LROW(0), w1 = LROW(1), w2 = LROW(2),
               w3 = LROW(3), w4 = LROW(4), w5 = LROW(5);
        for (int k0 = 0; k0 < KPB; k0 += 6) {           // KPB = 192 = 32 * 6
            FMAROW(k0 + 0, w0)  w0 = LCL(k0 + 6);
            FMAROW(k0 + 1, w1)  w1 = LCL(k0 + 7);
            FMAROW(k0 + 2, w2)  w2 = LCL(k0 + 8);
            FMAROW(k0 + 3, w3)  w3 = LCL(k0 + 9);
            FMAROW(k0 + 4, w4)  w4 = LCL(k0 + 10);
            FMAROW(k0 + 5, w5)  w5 = LCL(k0 + 11);
        }
#undef LCL
#undef LROW
    } else if (v0 < Vn) {
        // tail (last tile only): only .x can be valid (v0 = 50264); .yzw -> pad
        const float* __restrict__ wq = lm_W + (size_t)kb * Vn + v0;
        for (int k = 0; k < KPB; ++k) {
            const float wx = wq[(size_t)k * Vn];
            #pragma unroll
            for (int b = 0; b < Bn; ++b)
                acc[b].x = fmaf(s_me[k * Bn + b], wx, acc[b].x);
        }
    }
#undef FMAROW
#undef FMA4

    // coalesced partial stores; pad region (v >= Vn) may be unwritten/garbage -> never read
    if (v0 < Vn) {
        float* __restrict__ pb = partial + (size_t)(kc * Bn) * VNP + v0;
        #pragma unroll
        for (int b = 0; b < Bn; ++b)
            *(float4*)(pb + (size_t)b * VNP) = acc[b];
    }
}

// ---------------- Reduce: out[b][v] = sum_kc partial[kc][b][v] + lm_b[v]
__global__ __launch_bounds__(256) void lm_reduce(
    const float* __restrict__ partial, const float* __restrict__ lm_b,
    float* __restrict__ out)
{
    const int idx = blockIdx.x * 256 + threadIdx.x;   // over Bn * VNP
    const int b   = idx / VNP;
    const int v   = idx - b * VNP;
    if (v >= Vn) return;

    float s = 0.f;
    #pragma unroll
    for (int kc = 0; kc < KC; ++kc)
        s += partial[(size_t)(kc * Bn + b) * VNP + v];
    out[(size_t)b * Vn + v] = s + lm_b[v];
}

extern "C" void kernel_launch(void* const* d_in, const int* in_sizes, int n_in,
                              void* d_out, int out_size, void* d_ws, size_t ws_size,
                              hipStream_t stream) {
    const int*   batch_arg    = (const int*)  d_in[0];
    const int*   event_pos    = (const int*)  d_in[1];
    const int*   mask_indices = (const int*)  d_in[2];
    const float* sent_emb     = (const float*)d_in[3];
    const float* type_emb     = (const float*)d_in[4];
    const float* emb_table    = (const float*)d_in[5];
    const float* W1_1         = (const float*)d_in[6];
    const float* W1_2         = (const float*)d_in[7];
    const float* W2_1         = (const float*)d_in[8];
    const float* W2_2         = (const float*)d_in[9];
    const float* lm_W         = (const float*)d_in[10];
    const float* lm_b         = (const float*)d_in[11];
    float* out = (float*)d_out;

    float* o1_ws   = (float*)d_ws;                    // Bn*Hn floats
    float* me_t    = o1_ws + (size_t)Bn * Hn;         // Hn*Bn floats
    float* partial = me_t  + (size_t)Hn * Bn;         // KC*Bn*VNP floats (~13 MB)

    dim3 g12(Bn, Hn / 64);
    gate_layer1<<<g12, 256, 0, stream>>>(batch_arg, event_pos, mask_indices,
                                         sent_emb, emb_table, W1_1, W1_2, o1_ws);
    gate_layer2<<<g12, 256, 0, stream>>>(batch_arg, event_pos, mask_indices,
                                         type_emb, emb_table, W2_1, W2_2, o1_ws, me_t);

    dim3 gs(NVT, KC);
    lm_head_stream<<<gs, 256, 0, stream>>>(me_t, lm_W, partial);
    lm_reduce<<<(Bn * VNP + 255) / 256, 256, 0, stream>>>(partial, lm_b, out);
}

// Round 15
// 68.837 us; speedup vs baseline: 1.0963x; 1.0963x over previous
//
#include <hip/hip_runtime.h>

#define Hn 768
#define Bn 16
#define Sn 512
#define En 32
#define Vn 50265

#define KC   8            // k-chunks (split-K across blocks)
#define KPB  (Hn / KC)    // 96 k per block
#define VT   1024         // v per block (256 threads x 4 v float4)
#define NVT  50           // v tiles (50 * 1024 = 51200 >= Vn)
#define VNP  (NVT * VT)   // padded V for partials

// ---------------- Layer 1: o1 = g1*inst + (1-g1)*sent, g1 = sigmoid(inst@W1_1 + sent@W1_2)
__global__ __launch_bounds__(256) void gate_layer1(
    const int* __restrict__ batch_arg, const int* __restrict__ event_pos,
    const int* __restrict__ mask_indices, const float* __restrict__ sent_emb,
    const float* __restrict__ emb_table, const float* __restrict__ W1_1,
    const float* __restrict__ W1_2, float* __restrict__ o1_out)
{
    const int b  = blockIdx.x;
    const int j0 = threadIdx.x & 63;
    const int ks = threadIdx.x >> 6;           // wave-uniform
    const int j  = blockIdx.y * 64 + j0;

    const int mask = mask_indices[b];
    int estar = -1;
    #pragma unroll
    for (int e = 0; e < En; ++e)
        if (event_pos[b * En + e] == mask && estar < 0) estar = e;
    const int tok = batch_arg[b * Sn + mask];

    __shared__ __align__(16) float s_inst[Hn];
    __shared__ __align__(16) float s_sent[Hn];
    for (int t = threadIdx.x; t < Hn; t += 256) {
        s_inst[t] = emb_table[(size_t)tok * Hn + t];
        s_sent[t] = (estar >= 0) ? sent_emb[((size_t)b * En + estar) * Hn + t] : 0.f;
    }
    __syncthreads();

    float a0 = 0.f, a1 = 0.f, c0 = 0.f, c1 = 0.f;
    const float* __restrict__ w1 = W1_1 + (size_t)ks * 192 * Hn + j;
    const float* __restrict__ w2 = W1_2 + (size_t)ks * 192 * Hn + j;
    const float4* __restrict__ si = (const float4*)(s_inst + ks * 192);
    const float4* __restrict__ ss = (const float4*)(s_sent + ks * 192);
    #pragma unroll 4
    for (int k4 = 0; k4 < 48; ++k4) {
        const float4 iv = si[k4];
        const float4 sv = ss[k4];
        const float* __restrict__ wa = w1 + (size_t)k4 * 4 * Hn;
        const float* __restrict__ wb = w2 + (size_t)k4 * 4 * Hn;
        a0 = fmaf(iv.x, wa[0],      a0);
        a1 = fmaf(iv.y, wa[Hn],     a1);
        a0 = fmaf(iv.z, wa[2 * Hn], a0);
        a1 = fmaf(iv.w, wa[3 * Hn], a1);
        c0 = fmaf(sv.x, wb[0],      c0);
        c1 = fmaf(sv.y, wb[Hn],     c1);
        c0 = fmaf(sv.z, wb[2 * Hn], c0);
        c1 = fmaf(sv.w, wb[3 * Hn], c1);
    }

    __shared__ float r_a[4][64];
    __shared__ float r_c[4][64];
    r_a[ks][j0] = a0 + a1; r_c[ks][j0] = c0 + c1;
    __syncthreads();
    if (ks == 0) {
        const float A = r_a[0][j0] + r_a[1][j0] + r_a[2][j0] + r_a[3][j0];
        const float C = r_c[0][j0] + r_c[1][j0] + r_c[2][j0] + r_c[3][j0];
        const float g = 1.f / (1.f + expf(-(A + C)));
        o1_out[b * Hn + j] = g * s_inst[j] + (1.f - g) * s_sent[j];
    }
}

// ---------------- Layer 2: o2 = g2*o1 + (1-g2)*typ, written TRANSPOSED as me_t[k][b]
__global__ __launch_bounds__(256) void gate_layer2(
    const int* __restrict__ batch_arg, const int* __restrict__ event_pos,
    const int* __restrict__ mask_indices, const float* __restrict__ type_emb,
    const float* __restrict__ emb_table, const float* __restrict__ W2_1,
    const float* __restrict__ W2_2, const float* __restrict__ o1_in,
    float* __restrict__ me_t)
{
    const int b  = blockIdx.x;
    const int j0 = threadIdx.x & 63;
    const int ks = threadIdx.x >> 6;
    const int j  = blockIdx.y * 64 + j0;

    const int mask = mask_indices[b];
    int estar = -1;
    #pragma unroll
    for (int e = 0; e < En; ++e)
        if (event_pos[b * En + e] == mask && estar < 0) estar = e;
    const int tok = batch_arg[b * Sn + mask];

    __shared__ __align__(16) float s_o1[Hn];
    __shared__ __align__(16) float s_typ[Hn];
    for (int t = threadIdx.x; t < Hn; t += 256) {
        s_o1[t]  = o1_in[b * Hn + t];
        s_typ[t] = type_emb[((size_t)b * Sn + mask) * Hn + t];
    }
    __syncthreads();

    float a0 = 0.f, a1 = 0.f, c0 = 0.f, c1 = 0.f;
    const float* __restrict__ w1 = W2_1 + (size_t)ks * 192 * Hn + j;
    const float* __restrict__ w2 = W2_2 + (size_t)ks * 192 * Hn + j;
    const float4* __restrict__ so = (const float4*)(s_o1  + ks * 192);
    const float4* __restrict__ st = (const float4*)(s_typ + ks * 192);
    #pragma unroll 4
    for (int k4 = 0; k4 < 48; ++k4) {
        const float4 ov = so[k4];
        const float4 tv = st[k4];
        const float* __restrict__ wa = w1 + (size_t)k4 * 4 * Hn;
        const float* __restrict__ wb = w2 + (size_t)k4 * 4 * Hn;
        a0 = fmaf(ov.x, wa[0],      a0);
        a1 = fmaf(ov.y, wa[Hn],     a1);
        a0 = fmaf(ov.z, wa[2 * Hn], a0);
        a1 = fmaf(ov.w, wa[3 * Hn], a1);
        c0 = fmaf(tv.x, wb[0],      c0);
        c1 = fmaf(tv.y, wb[Hn],     c1);
        c0 = fmaf(tv.z, wb[2 * Hn], c0);
        c1 = fmaf(tv.w, wb[3 * Hn], c1);
    }

    __shared__ float r_a[4][64];
    __shared__ float r_c[4][64];
    r_a[ks][j0] = a0 + a1; r_c[ks][j0] = c0 + c1;
    __syncthreads();
    if (ks == 0) {
        const float A = r_a[0][j0] + r_a[1][j0] + r_a[2][j0] + r_a[3][j0];
        const float C = r_c[0][j0] + r_c[1][j0] + r_c[2][j0] + r_c[3][j0];
        const float g = 1.f / (1.f + expf(-(A + C)));
        float o2 = g * s_o1[j] + (1.f - g) * s_typ[j];
        if (estar < 0) o2 = emb_table[(size_t)tok * Hn + j];  // mask row never updated
        me_t[j * Bn + b] = o2;
    }
}

// ---------------- LM head partials: partial[kc][b][v] = sum_{k in chunk} me[k][b]*lm_W[k][v]
// Grid (50, 8) = 400 blocks x 256 threads = 102k threads (~2 blocks/CU, all
// co-resident, no tail). Thread = 4 v (float4) x 16 b. Ring-3 named prefetch:
// slot reloaded right after its FMAs -> counted vmcnt waits, 2-3 loads in
// flight per thread => ~4-5 MB chip-wide (Little's law for ~6 TB/s).
// Block reads 4 KB contiguous per k-row (burst-friendly linear sweep).
__global__ __launch_bounds__(256) void lm_head_stream(
    const float* __restrict__ me_t, const float* __restrict__ lm_W,
    float* __restrict__ partial)
{
    __shared__ __align__(16) float s_me[KPB * Bn];   // 6 KB me slice for this chunk

    const int tid = threadIdx.x;
    const int kc  = blockIdx.y;
    const int kb  = kc * KPB;
    const int v0  = blockIdx.x * VT + tid * 4;

    for (int i = tid; i < KPB * Bn / 4; i += 256)    // 384 float4, coalesced
        ((float4*)s_me)[i] = ((const float4*)(me_t + kb * Bn))[i];
    __syncthreads();

    float4 acc[Bn];
    #pragma unroll
    for (int i = 0; i < Bn; ++i) acc[i] = make_float4(0.f, 0.f, 0.f, 0.f);

#define FMA4(i, s)                                                            \
    acc[i].x = fmaf(s, wv.x, acc[i].x); acc[i].y = fmaf(s, wv.y, acc[i].y);   \
    acc[i].z = fmaf(s, wv.z, acc[i].z); acc[i].w = fmaf(s, wv.w, acc[i].w);

#define FMAROW(kk, wreg)                                                      \
    {                                                                         \
        const float4 wv = wreg;                                               \
        const float4* __restrict__ m = (const float4*)(s_me + (kk) * Bn);     \
        const float4 m0 = m[0], m1 = m[1], m2 = m[2], m3 = m[3];              \
        FMA4(0,  m0.x) FMA4(1,  m0.y) FMA4(2,  m0.z) FMA4(3,  m0.w)          \
        FMA4(4,  m1.x) FMA4(5,  m1.y) FMA4(6,  m1.z) FMA4(7,  m1.w)          \
        FMA4(8,  m2.x) FMA4(9,  m2.y) FMA4(10, m2.z) FMA4(11, m2.w)          \
        FMA4(12, m3.x) FMA4(13, m3.y) FMA4(14, m3.z) FMA4(15, m3.w)          \
    }

    if (v0 + 3 < Vn) {
        const float* __restrict__ wp = lm_W + (size_t)kb * Vn + v0;
#define LROW(kk) (*(const float4*)(wp + (size_t)(kk) * Vn))
#define LCL(kk)  LROW((kk) < KPB ? (kk) : (KPB - 1))   // clamp: redundant at tail
        float4 w0 = LROW(0), w1 = LROW(1), w2 = LROW(2);
        for (int k0 = 0; k0 < KPB; k0 += 3) {           // KPB = 96 = 32 * 3
            FMAROW(k0 + 0, w0)  w0 = LCL(k0 + 3);
            FMAROW(k0 + 1, w1)  w1 = LCL(k0 + 4);
            FMAROW(k0 + 2, w2)  w2 = LCL(k0 + 5);
        }
#undef LCL
#undef LROW
    } else if (v0 < Vn) {
        // tail (last tile only): only .x can be valid (v0 = 50264); .yzw -> pad
        const float* __restrict__ wq = lm_W + (size_t)kb * Vn + v0;
        for (int k = 0; k < KPB; ++k) {
            const float wx = wq[(size_t)k * Vn];
            #pragma unroll
            for (int b = 0; b < Bn; ++b)
                acc[b].x = fmaf(s_me[k * Bn + b], wx, acc[b].x);
        }
    }
#undef FMAROW
#undef FMA4

    // coalesced partial stores; pad region (v >= Vn) never read by reduce
    if (v0 < Vn) {
        float* __restrict__ pb = partial + (size_t)(kc * Bn) * VNP + v0;
        #pragma unroll
        for (int b = 0; b < Bn; ++b)
            *(float4*)(pb + (size_t)b * VNP) = acc[b];
    }
}

// ---------------- Reduce: out[b][v] = sum_kc partial[kc][b][v] + lm_b[v]
__global__ __launch_bounds__(256) void lm_reduce(
    const float* __restrict__ partial, const float* __restrict__ lm_b,
    float* __restrict__ out)
{
    const int idx = blockIdx.x * 256 + threadIdx.x;   // over Bn * VNP
    const int b   = idx / VNP;
    const int v   = idx - b * VNP;
    if (v >= Vn) return;

    float s = 0.f;
    #pragma unroll
    for (int kc = 0; kc < KC; ++kc)
        s += partial[(size_t)(kc * Bn + b) * VNP + v];
    out[(size_t)b * Vn + v] = s + lm_b[v];
}

extern "C" void kernel_launch(void* const* d_in, const int* in_sizes, int n_in,
                              void* d_out, int out_size, void* d_ws, size_t ws_size,
                              hipStream_t stream) {
    const int*   batch_arg    = (const int*)  d_in[0];
    const int*   event_pos    = (const int*)  d_in[1];
    const int*   mask_indices = (const int*)  d_in[2];
    const float* sent_emb     = (const float*)d_in[3];
    const float* type_emb     = (const float*)d_in[4];
    const float* emb_table    = (const float*)d_in[5];
    const float* W1_1         = (const float*)d_in[6];
    const float* W1_2         = (const float*)d_in[7];
    const float* W2_1         = (const float*)d_in[8];
    const float* W2_2         = (const float*)d_in[9];
    const float* lm_W         = (const float*)d_in[10];
    const float* lm_b         = (const float*)d_in[11];
    float* out = (float*)d_out;

    float* o1_ws   = (float*)d_ws;                    // Bn*Hn floats
    float* me_t    = o1_ws + (size_t)Bn * Hn;         // Hn*Bn floats
    float* partial = me_t  + (size_t)Hn * Bn;         // KC*Bn*VNP floats (~26 MB)

    dim3 g12(Bn, Hn / 64);
    gate_layer1<<<g12, 256, 0, stream>>>(batch_arg, event_pos, mask_indices,
                                         sent_emb, emb_table, W1_1, W1_2, o1_ws);
    gate_layer2<<<g12, 256, 0, stream>>>(batch_arg, event_pos, mask_indices,
                                         type_emb, emb_table, W2_1, W2_2, o1_ws, me_t);

    dim3 gs(NVT, KC);
    lm_head_stream<<<gs, 256, 0, stream>>>(me_t, lm_W, partial);
    lm_reduce<<<(Bn * VNP + 255) / 256, 256, 0, stream>>>(partial, lm_b, out);
}